// Round 3
// baseline (1047.808 us; speedup 1.0000x reference)
//
#include <hip/hip_runtime.h>
#include <cstddef>

// Problem constants (B=4, H=W=64, C=512, heads=8, head_dim=64, SR=2)
#define NTOK 4096   // 64*64 query tokens per batch
#define DNKV 1024   // 32*32 kv tokens per batch

// XOR swizzle for a 64-wide LDS tile: element (r,c) -> flat index.
// Keeps float4 groups contiguous+aligned, spreads transposed scalar stores.
__device__ __forceinline__ int swz(int r, int c) {
  return (r << 6) + ((((c >> 2) ^ (r >> 2)) & 15) << 2) + (c & 3);
}

// ---------------- generic fp32 GEMM: C[M,N] = A[M,K] @ B[K,N] ----------------
// 64x64 block tile, BK=32, 256 threads, 4x4 per thread.
__global__ __launch_bounds__(256)
void gemm_f32(const float* __restrict__ A, const float* __restrict__ B,
              float* __restrict__ C, int M, int N, int K) {
  __shared__ float As[32 * 64];   // [k][m] transposed, swizzled
  __shared__ float Bs[32 * 64];   // [k][n] natural
  const int t  = threadIdx.x;
  const int tx = t & 15, ty = t >> 4;
  const int m0 = blockIdx.y << 6, n0 = blockIdx.x << 6;
  float acc[4][4] = {};
  for (int k0 = 0; k0 < K; k0 += 32) {
    #pragma unroll
    for (int l = 0; l < 2; ++l) {
      int s  = t + (l << 8);
      int ra = s >> 3, ca = s & 7;                 // A tile: 64 rows x 8 col4
      float4 av = *(const float4*)&A[(size_t)(m0 + ra) * K + k0 + (ca << 2)];
      int kb = ca << 2;
      As[swz(kb + 0, ra)] = av.x;
      As[swz(kb + 1, ra)] = av.y;
      As[swz(kb + 2, ra)] = av.z;
      As[swz(kb + 3, ra)] = av.w;
      int rb = s >> 4, cb = s & 15;                // B tile: 32 rows x 16 col4
      *(float4*)&Bs[(rb << 6) + (cb << 2)] =
          *(const float4*)&B[(size_t)(k0 + rb) * N + n0 + (cb << 2)];
    }
    __syncthreads();
    #pragma unroll
    for (int kk = 0; kk < 32; ++kk) {
      float a[4], b[4];
      *(float4*)a = *(const float4*)&As[swz(kk, ty << 2)];
      *(float4*)b = *(const float4*)&Bs[(kk << 6) + (tx << 2)];
      #pragma unroll
      for (int i = 0; i < 4; ++i)
        #pragma unroll
        for (int j = 0; j < 4; ++j)
          acc[i][j] = fmaf(a[i], b[j], acc[i][j]);
    }
    __syncthreads();
  }
  #pragma unroll
  for (int i = 0; i < 4; ++i) {
    float4 o = make_float4(acc[i][0], acc[i][1], acc[i][2], acc[i][3]);
    *(float4*)&C[(size_t)(m0 + (ty << 2) + i) * N + n0 + (tx << 2)] = o;
  }
}

// ------------- conv (2x2, stride 2, no pad) as gathered GEMM -------------
// C[4096,512] = A[4096,2048] @ W[2048,512]; A gathered from x[4,64,64,512].
// Row m = b*1024 + oi*32 + oj; col k = (di*2+dj)*512 + cin.
__global__ __launch_bounds__(256)
void conv_gemm(const float* __restrict__ x, const float* __restrict__ w,
               float* __restrict__ C) {
  __shared__ float As[32 * 64];
  __shared__ float Bs[32 * 64];
  const int t  = threadIdx.x;
  const int tx = t & 15, ty = t >> 4;
  const int m0 = blockIdx.y << 6, n0 = blockIdx.x << 6;
  float acc[4][4] = {};
  for (int k0 = 0; k0 < 2048; k0 += 32) {
    const int di = k0 >> 10, dj = (k0 >> 9) & 1;   // constant within a K-tile
    const int cin0 = k0 & 511;
    #pragma unroll
    for (int l = 0; l < 2; ++l) {
      int s  = t + (l << 8);
      int ra = s >> 3, ca = s & 7;
      int m  = m0 + ra;
      int bb = m >> 10, oi = (m >> 5) & 31, oj = m & 31;
      const float* ap = x + (((size_t)(bb * 64 + 2 * oi + di)) * 64 +
                             (2 * oj + dj)) * 512 + cin0 + (ca << 2);
      float4 av = *(const float4*)ap;
      int kb = ca << 2;
      As[swz(kb + 0, ra)] = av.x;
      As[swz(kb + 1, ra)] = av.y;
      As[swz(kb + 2, ra)] = av.z;
      As[swz(kb + 3, ra)] = av.w;
      int rb = s >> 4, cb = s & 15;
      *(float4*)&Bs[(rb << 6) + (cb << 2)] =
          *(const float4*)&w[(size_t)(k0 + rb) * 512 + n0 + (cb << 2)];
    }
    __syncthreads();
    #pragma unroll
    for (int kk = 0; kk < 32; ++kk) {
      float a[4], b[4];
      *(float4*)a = *(const float4*)&As[swz(kk, ty << 2)];
      *(float4*)b = *(const float4*)&Bs[(kk << 6) + (tx << 2)];
      #pragma unroll
      for (int i = 0; i < 4; ++i)
        #pragma unroll
        for (int j = 0; j < 4; ++j)
          acc[i][j] = fmaf(a[i], b[j], acc[i][j]);
    }
    __syncthreads();
  }
  #pragma unroll
  for (int i = 0; i < 4; ++i) {
    float4 o = make_float4(acc[i][0], acc[i][1], acc[i][2], acc[i][3]);
    *(float4*)&C[(size_t)(m0 + (ty << 2) + i) * 512 + n0 + (tx << 2)] = o;
  }
}

// ------------- in-place LayerNorm over rows of X[rows,512] -------------
__global__ __launch_bounds__(256)
void ln_rows(float* __restrict__ X, const float* __restrict__ g,
             const float* __restrict__ be) {
  const int row = blockIdx.x;
  float* xr = X + (size_t)row * 512;
  const int t = threadIdx.x;
  float2 v = *(const float2*)&xr[2 * t];
  float s = v.x + v.y;
  #pragma unroll
  for (int m = 1; m < 64; m <<= 1) s += __shfl_xor(s, m);
  __shared__ float red1[4], red2[4];
  const int w = t >> 6, lane = t & 63;
  if (lane == 0) red1[w] = s;
  __syncthreads();
  const float mu = (red1[0] + red1[1] + red1[2] + red1[3]) * (1.0f / 512.0f);
  const float dx = v.x - mu, dy = v.y - mu;
  float q = dx * dx + dy * dy;
  #pragma unroll
  for (int m = 1; m < 64; m <<= 1) q += __shfl_xor(q, m);
  if (lane == 0) red2[w] = q;
  __syncthreads();
  const float var = (red2[0] + red2[1] + red2[2] + red2[3]) * (1.0f / 512.0f);
  const float rs = rsqrtf(var + 1e-4f);
  float2 gg = *(const float2*)&g[2 * t];
  float2 bb = *(const float2*)&be[2 * t];
  float2 o;
  o.x = gg.x * dx * rs + bb.x;
  o.y = gg.y * dy * rs + bb.y;
  *(float2*)&xr[2 * t] = o;
}

// ------------- ||k||^2 per (b,h,m): nb[b*8192 + h*1024 + m] -------------
__global__ __launch_bounds__(256)
void knorm(const float* __restrict__ kv, float* __restrict__ nb) {
  const int i = blockIdx.x * 256 + threadIdx.x;     // 32768 total
  const int b = i >> 13, h = (i >> 10) & 7, m = i & 1023;
  const float* kr = kv + ((size_t)(b * DNKV + m)) * 1024 + h * 64;
  float s = 0.f;
  #pragma unroll
  for (int j = 0; j < 16; ++j) {
    float4 a = *(const float4*)&kr[j << 2];
    s += a.x * a.x + a.y * a.y + a.z * a.z + a.w * a.w;
  }
  nb[i] = s;
}

// ------------- attention: one block per (b,h, 64-query tile) -------------
// score = sqrt(max(na+nb-2qk,1e-7))*0.125 ; single-pass softmax (no max-sub:
// scores are bounded ~[0,1.5], exp cannot overflow).
__global__ __launch_bounds__(256)
void attn_f32(const float* __restrict__ qbuf, const float* __restrict__ kvbuf,
              const float* __restrict__ nbuf, float* __restrict__ aout) {
  __shared__ float Qs[64 * 64];   // transposed [d][q], swizzled
  __shared__ float KVs[64 * 64];  // K-phase: [d][m] swz; V-phase: [m][j] swz
  __shared__ float Ps[64 * 64];   // natural [q][m]
  const int t  = threadIdx.x;
  const int tx = t & 15, ty = t >> 4;
  const int n0 = blockIdx.x << 6;
  const int bh = blockIdx.y;
  const int b  = bh >> 3, h = bh & 7;
  const float* qp = qbuf + ((size_t)b * NTOK + n0) * 512 + h * 64;
  const float* kp = kvbuf + (size_t)b * DNKV * 1024 + h * 64;

  // stage Q tile (64 q x 64 d), transposed+swizzled
  #pragma unroll
  for (int l = 0; l < 4; ++l) {
    int s = t + (l << 8);
    int row = s >> 4, c4 = s & 15;
    float4 qv = *(const float4*)&qp[(size_t)row * 512 + (c4 << 2)];
    int d0 = c4 << 2;
    Qs[swz(d0 + 0, row)] = qv.x;
    Qs[swz(d0 + 1, row)] = qv.y;
    Qs[swz(d0 + 2, row)] = qv.z;
    Qs[swz(d0 + 3, row)] = qv.w;
  }
  __syncthreads();

  // ||q||^2 for this thread's 4 rows
  float na[4] = {0.f, 0.f, 0.f, 0.f};
  #pragma unroll
  for (int d = 0; d < 64; ++d) {
    float qa[4];
    *(float4*)qa = *(const float4*)&Qs[swz(d, ty << 2)];
    na[0] += qa[0] * qa[0];
    na[1] += qa[1] * qa[1];
    na[2] += qa[2] * qa[2];
    na[3] += qa[3] * qa[3];
  }

  float oacc[4][4] = {};
  float rowsum[4] = {0.f, 0.f, 0.f, 0.f};

  for (int mt = 0; mt < 16; ++mt) {
    const int m0 = mt << 6;
    // stage K tile transposed+swizzled: KVs[d][m]
    #pragma unroll
    for (int l = 0; l < 4; ++l) {
      int s = t + (l << 8);
      int row = s >> 4, c4 = s & 15;
      float4 kvv = *(const float4*)&kp[(size_t)(m0 + row) * 1024 + (c4 << 2)];
      int d0 = c4 << 2;
      KVs[swz(d0 + 0, row)] = kvv.x;
      KVs[swz(d0 + 1, row)] = kvv.y;
      KVs[swz(d0 + 2, row)] = kvv.z;
      KVs[swz(d0 + 3, row)] = kvv.w;
    }
    float nb[4];
    #pragma unroll
    for (int j = 0; j < 4; ++j)
      nb[j] = nbuf[(size_t)bh * DNKV + m0 + (tx << 2) + j];
    __syncthreads();

    // S = Q K^T (contract d)
    float sacc[4][4] = {};
    #pragma unroll
    for (int d = 0; d < 64; ++d) {
      float qa[4], kb[4];
      *(float4*)qa = *(const float4*)&Qs[swz(d, ty << 2)];
      *(float4*)kb = *(const float4*)&KVs[swz(d, tx << 2)];
      #pragma unroll
      for (int i = 0; i < 4; ++i)
        #pragma unroll
        for (int j = 0; j < 4; ++j)
          sacc[i][j] = fmaf(qa[i], kb[j], sacc[i][j]);
    }

    // transform to P = exp(sqrt(max(d2,eps))*scale), write Ps
    #pragma unroll
    for (int i = 0; i < 4; ++i) {
      float pr[4];
      #pragma unroll
      for (int j = 0; j < 4; ++j) {
        float d2 = na[i] + nb[j] - 2.0f * sacc[i][j];
        float sc = sqrtf(fmaxf(d2, 1e-7f)) * 0.125f;
        float p  = __expf(sc);
        rowsum[i] += p;
        pr[j] = p;
      }
      *(float4*)&Ps[(((ty << 2) + i) << 6) + (tx << 2)] = *(float4*)pr;
    }
    __syncthreads();   // S-GEMM reads of KVs done; Ps complete

    // stage V tile natural+swizzled into the same buffer: KVs[m][j]
    #pragma unroll
    for (int l = 0; l < 4; ++l) {
      int s = t + (l << 8);
      int row = s >> 4, c4 = s & 15;
      float4 vv = *(const float4*)&kp[(size_t)(m0 + row) * 1024 + 512 + (c4 << 2)];
      *(float4*)&KVs[swz(row, c4 << 2)] = vv;
    }
    __syncthreads();

    // O += P V (contract m)
    #pragma unroll
    for (int mg = 0; mg < 16; ++mg) {
      float pa[4][4];
      #pragma unroll
      for (int i = 0; i < 4; ++i)
        *(float4*)pa[i] = *(const float4*)&Ps[(((ty << 2) + i) << 6) + (mg << 2)];
      #pragma unroll
      for (int mm = 0; mm < 4; ++mm) {
        float vv[4];
        *(float4*)vv = *(const float4*)&KVs[swz((mg << 2) + mm, tx << 2)];
        #pragma unroll
        for (int i = 0; i < 4; ++i)
          #pragma unroll
          for (int j = 0; j < 4; ++j)
            oacc[i][j] = fmaf(pa[i][mm], vv[j], oacc[i][j]);
      }
    }
    __syncthreads();   // PV reads done before next tile overwrites KVs
  }

  // reduce rowsum across the 16 tx lanes of each ty group
  #pragma unroll
  for (int i = 0; i < 4; ++i) {
    float r = rowsum[i];
    r += __shfl_xor(r, 1);
    r += __shfl_xor(r, 2);
    r += __shfl_xor(r, 4);
    r += __shfl_xor(r, 8);
    rowsum[i] = 1.0f / r;
  }
  float* op = aout + ((size_t)b * NTOK + n0) * 512 + h * 64;
  #pragma unroll
  for (int i = 0; i < 4; ++i) {
    float4 o = make_float4(oacc[i][0] * rowsum[i], oacc[i][1] * rowsum[i],
                           oacc[i][2] * rowsum[i], oacc[i][3] * rowsum[i]);
    *(float4*)&op[(size_t)((ty << 2) + i) * 512 + (tx << 2)] = o;
  }
}

extern "C" void kernel_launch(void* const* d_in, const int* in_sizes, int n_in,
                              void* d_out, int out_size, void* d_ws, size_t ws_size,
                              hipStream_t stream) {
  const float* x     = (const float*)d_in[0];
  const float* Wq    = (const float*)d_in[1];
  const float* Wkv   = (const float*)d_in[2];
  const float* convw = (const float*)d_in[3];
  const float* gamma = (const float*)d_in[4];
  const float* beta  = (const float*)d_in[5];
  const float* Wproj = (const float*)d_in[6];
  float* out = (float*)d_out;
  float* ws  = (float*)d_ws;

  // Buffer plan (workspace slimmed 80.1 -> 48.1 MiB to avoid any chance of
  // overrunning ws_size — a ws overflow faults the GPU and kills the
  // container):
  //   qbuf lives in d_out (exactly out_size = 8,388,608 floats). Written by
  //   kernel 1, read-only during attention, dead before kernel 7 overwrites
  //   d_out with the final result. Stream ordering => no overlap.
  float* qbuf  = out;                   // [4,4096,512]  (aliases d_out)
  float* kvbuf = ws;                    // [4,1024,1024] 4,194,304 floats
  float* nbuf  = ws + 4194304;          // [4,8,1024]       32,768 floats
  float* aout  = ws + 4227072;          // [4,4096,512]  8,388,608 floats
  float* xln   = aout;                  // [4,1024,512] reuses aout region
                                        // (dead before attention writes aout)

  // 1. q projection -> d_out (used as qbuf)
  gemm_f32<<<dim3(8, 256), 256, 0, stream>>>(x, Wq, qbuf, 16384, 512, 512);
  // 2. SR conv (gathered GEMM) -> xln
  conv_gemm<<<dim3(8, 64), 256, 0, stream>>>(x, convw, xln);
  // 3. LayerNorm in-place
  ln_rows<<<dim3(4096), 256, 0, stream>>>(xln, gamma, beta);
  // 4. kv projection
  gemm_f32<<<dim3(16, 64), 256, 0, stream>>>(xln, Wkv, kvbuf, 4096, 1024, 512);
  // 5. ||k||^2
  knorm<<<dim3(128), 256, 0, stream>>>(kvbuf, nbuf);
  // 6. L2-distance attention: reads qbuf(d_out), writes aout(ws)
  attn_f32<<<dim3(64, 32), 256, 0, stream>>>(qbuf, kvbuf, nbuf, aout);
  // 7. output projection: reads aout(ws), overwrites d_out with final result
  gemm_f32<<<dim3(8, 256), 256, 0, stream>>>(aout, Wproj, out, 16384, 512, 512);
}

// Round 8
// 513.111 us; speedup vs baseline: 2.0421x; 2.0421x over previous
//
#include <hip/hip_runtime.h>
#include <cstddef>

// Problem constants (B=4, H=W=64, C=512, heads=8, head_dim=64, SR=2)
// Strategy: all GEMM-shaped compute on MFMA via split-bf16 (3-MFMA trick):
//   x = hi + lo (bf16 each);  x*y ~= xh*yh + xh*yl + xl*yh  (fp32 accum)
// -> fp32-grade accuracy at ~5x the fp32 vector-ALU FLOP rate.

typedef float  f32x4 __attribute__((ext_vector_type(4)));
typedef short  bh8   __attribute__((ext_vector_type(8)));

__device__ __forceinline__ ushort f2bh(float f) {        // fp32 -> bf16 (RNE)
  uint u = __float_as_uint(f);
  return (ushort)((u + 0x7fffu + ((u >> 16) & 1u)) >> 16);
}
__device__ __forceinline__ float bh2f(ushort h) {
  return __uint_as_float(((uint)h) << 16);
}
__device__ __forceinline__ void split2(float f, ushort& hi, ushort& lo) {
  hi = f2bh(f);
  lo = f2bh(f - bh2f(hi));
}

#define MFMA16(a, b, c) __builtin_amdgcn_mfma_f32_16x16x32_bf16((a), (b), (c), 0, 0, 0)

// ---------- prep: W[K][N] fp32 -> WT_hi[N][K], WT_lo[N][K] bf16 ----------
__global__ __launch_bounds__(256)
void prep_wT(const float* __restrict__ W, ushort* __restrict__ Th,
             ushort* __restrict__ Tl, int K, int N) {
  int idx = blockIdx.x * 256 + threadIdx.x;
  int kq = K >> 2;
  if (idx >= N * kq) return;
  int n = idx / kq, k4 = (idx % kq) << 2;
  ushort4 h, l;
  float v;
  v = W[(size_t)(k4 + 0) * N + n]; split2(v, h.x, l.x);
  v = W[(size_t)(k4 + 1) * N + n]; split2(v, h.y, l.y);
  v = W[(size_t)(k4 + 2) * N + n]; split2(v, h.z, l.z);
  v = W[(size_t)(k4 + 3) * N + n]; split2(v, h.w, l.w);
  *(ushort4*)&Th[(size_t)n * K + k4] = h;
  *(ushort4*)&Tl[(size_t)n * K + k4] = l;
}

// ---------- split-bf16 MFMA GEMM: C[M,N] = A[M,K] @ B[K,N] ----------
// 128x128 tile, BK=32, 256 thr (4 waves in 2x2), 4x4 16x16 subtiles/wave.
// B comes pre-transposed+split (Bh/Bl = [N][K] bf16). A converted in staging.
// MODE 0: plain fp32 C store.  MODE 1: kv split-store (K row-major bf16 hi/lo,
// V transposed per-head bf16 hi/lo) for the attention kernel.
template <int MODE>
__global__ __launch_bounds__(256)
void gemm_bf3(const float* __restrict__ A, const ushort* __restrict__ Bh,
              const ushort* __restrict__ Bl, float* __restrict__ C,
              int M, int N, int K,
              ushort* __restrict__ kh, ushort* __restrict__ kl,
              ushort* __restrict__ vth, ushort* __restrict__ vtl) {
  __shared__ ushort Ah[128][40], Al[128][40], Bth[128][40], Btl[128][40];
  const int t = threadIdx.x;
  const int lane = t & 63, w = t >> 6;
  const int wm = (w >> 1) << 6, wn = (w & 1) << 6;
  const int g = lane >> 4, cl = lane & 15;
  const int m0 = blockIdx.y << 7, n0 = blockIdx.x << 7;
  f32x4 acc[4][4];
  #pragma unroll
  for (int i = 0; i < 4; ++i)
    #pragma unroll
    for (int j = 0; j < 4; ++j) acc[i][j] = (f32x4)0.f;

  for (int k0 = 0; k0 < K; k0 += 32) {
    __syncthreads();
    // stage A (fp32 -> hi/lo bf16)
    #pragma unroll
    for (int i = 0; i < 4; ++i) {
      int f = (i << 8) + t, row = f >> 3, kq = (f & 7) << 2;
      float4 av = *(const float4*)&A[(size_t)(m0 + row) * K + k0 + kq];
      ushort4 hh, ll;
      split2(av.x, hh.x, ll.x); split2(av.y, hh.y, ll.y);
      split2(av.z, hh.z, ll.z); split2(av.w, hh.w, ll.w);
      *(ushort4*)&Ah[row][kq] = hh;
      *(ushort4*)&Al[row][kq] = ll;
    }
    // stage B (already bf16 hi/lo, pre-transposed [N][K])
    {
      int row = t >> 1, hf = (t & 1) << 4;
      const ushort* bp = &Bh[(size_t)(n0 + row) * K + k0 + hf];
      *(uint4*)&Bth[row][hf]     = *(const uint4*)bp;
      *(uint4*)&Bth[row][hf + 8] = *(const uint4*)(bp + 8);
      const ushort* bq = &Bl[(size_t)(n0 + row) * K + k0 + hf];
      *(uint4*)&Btl[row][hf]     = *(const uint4*)bq;
      *(uint4*)&Btl[row][hf + 8] = *(const uint4*)(bq + 8);
    }
    __syncthreads();

    bh8 ah[4], al[4];
    #pragma unroll
    for (int ms = 0; ms < 4; ++ms) {
      ah[ms] = *(const bh8*)&Ah[wm + (ms << 4) + cl][g << 3];
      al[ms] = *(const bh8*)&Al[wm + (ms << 4) + cl][g << 3];
    }
    #pragma unroll
    for (int ns = 0; ns < 4; ++ns) {
      bh8 bh_ = *(const bh8*)&Bth[wn + (ns << 4) + cl][g << 3];
      bh8 bl_ = *(const bh8*)&Btl[wn + (ns << 4) + cl][g << 3];
      #pragma unroll
      for (int ms = 0; ms < 4; ++ms) {
        acc[ms][ns] = MFMA16(ah[ms], bh_, acc[ms][ns]);
        acc[ms][ns] = MFMA16(ah[ms], bl_, acc[ms][ns]);
        acc[ms][ns] = MFMA16(al[ms], bh_, acc[ms][ns]);
      }
    }
  }

  // epilogue. D layout: col = lane&15, row = (lane>>4)*4 + r  (m89-verified)
  #pragma unroll
  for (int ms = 0; ms < 4; ++ms)
    #pragma unroll
    for (int ns = 0; ns < 4; ++ns)
      #pragma unroll
      for (int r = 0; r < 4; ++r) {
        int row = m0 + wm + (ms << 4) + (g << 2) + r;
        int col = n0 + wn + (ns << 4) + cl;
        float v = acc[ms][ns][r];
        if (MODE == 0) {
          C[(size_t)row * N + col] = v;
        } else {
          int b = row >> 10, mm = row & 1023;
          ushort hh, ll;
          split2(v, hh, ll);
          if (col < 512) {                       // K part: [b][m][h*64+d]
            size_t o = ((size_t)(b * 1024 + mm)) * 512 + col;
            kh[o] = hh; kl[o] = ll;
          } else {                               // V part, transposed: [b][h][d][m]
            int h_ = (col - 512) >> 6, d = (col - 512) & 63;
            size_t o = (((size_t)(b * 8 + h_) << 6) + d) * 1024 + mm;
            vth[o] = hh; vtl[o] = ll;
          }
        }
      }
}

// ---------- conv (2x2 s2, no pad) as gathered split-bf16 GEMM ----------
// C[4096,512] = gather(x)[4096,2048] @ convW[2048,512]; B pre-transposed+split.
__global__ __launch_bounds__(256)
void conv_bf3(const float* __restrict__ x, const ushort* __restrict__ Bh,
              const ushort* __restrict__ Bl, float* __restrict__ C) {
  __shared__ ushort Ah[128][40], Al[128][40], Bth[128][40], Btl[128][40];
  const int t = threadIdx.x;
  const int lane = t & 63, w = t >> 6;
  const int wm = (w >> 1) << 6, wn = (w & 1) << 6;
  const int g = lane >> 4, cl = lane & 15;
  const int m0 = blockIdx.y << 7, n0 = blockIdx.x << 7;
  f32x4 acc[4][4];
  #pragma unroll
  for (int i = 0; i < 4; ++i)
    #pragma unroll
    for (int j = 0; j < 4; ++j) acc[i][j] = (f32x4)0.f;

  for (int k0 = 0; k0 < 2048; k0 += 32) {
    const int di = k0 >> 10, dj = (k0 >> 9) & 1, cin0 = k0 & 511;
    __syncthreads();
    #pragma unroll
    for (int i = 0; i < 4; ++i) {
      int f = (i << 8) + t, row = f >> 3, kq = (f & 7) << 2;
      int m = m0 + row;
      int bb = m >> 10, oi = (m >> 5) & 31, oj = m & 31;
      const float* ap = &x[(((size_t)(bb * 64 + 2 * oi + di)) * 64 +
                            (2 * oj + dj)) * 512 + cin0 + kq];
      float4 av = *(const float4*)ap;
      ushort4 hh, ll;
      split2(av.x, hh.x, ll.x); split2(av.y, hh.y, ll.y);
      split2(av.z, hh.z, ll.z); split2(av.w, hh.w, ll.w);
      *(ushort4*)&Ah[row][kq] = hh;
      *(ushort4*)&Al[row][kq] = ll;
    }
    {
      int row = t >> 1, hf = (t & 1) << 4;
      const ushort* bp = &Bh[(size_t)(n0 + row) * 2048 + k0 + hf];
      *(uint4*)&Bth[row][hf]     = *(const uint4*)bp;
      *(uint4*)&Bth[row][hf + 8] = *(const uint4*)(bp + 8);
      const ushort* bq = &Bl[(size_t)(n0 + row) * 2048 + k0 + hf];
      *(uint4*)&Btl[row][hf]     = *(const uint4*)bq;
      *(uint4*)&Btl[row][hf + 8] = *(const uint4*)(bq + 8);
    }
    __syncthreads();

    bh8 ah[4], al[4];
    #pragma unroll
    for (int ms = 0; ms < 4; ++ms) {
      ah[ms] = *(const bh8*)&Ah[wm + (ms << 4) + cl][g << 3];
      al[ms] = *(const bh8*)&Al[wm + (ms << 4) + cl][g << 3];
    }
    #pragma unroll
    for (int ns = 0; ns < 4; ++ns) {
      bh8 bh_ = *(const bh8*)&Bth[wn + (ns << 4) + cl][g << 3];
      bh8 bl_ = *(const bh8*)&Btl[wn + (ns << 4) + cl][g << 3];
      #pragma unroll
      for (int ms = 0; ms < 4; ++ms) {
        acc[ms][ns] = MFMA16(ah[ms], bh_, acc[ms][ns]);
        acc[ms][ns] = MFMA16(ah[ms], bl_, acc[ms][ns]);
        acc[ms][ns] = MFMA16(al[ms], bh_, acc[ms][ns]);
      }
    }
  }
  #pragma unroll
  for (int ms = 0; ms < 4; ++ms)
    #pragma unroll
    for (int ns = 0; ns < 4; ++ns)
      #pragma unroll
      for (int r = 0; r < 4; ++r)
        C[(size_t)(m0 + wm + (ms << 4) + (g << 2) + r) * 512 +
          n0 + wn + (ns << 4) + cl] = acc[ms][ns][r];
}

// ---------- in-place LayerNorm over rows of X[rows,512] ----------
__global__ __launch_bounds__(256)
void ln_rows(float* __restrict__ X, const float* __restrict__ gam,
             const float* __restrict__ be) {
  const int row = blockIdx.x;
  float* xr = X + (size_t)row * 512;
  const int t = threadIdx.x;
  float2 v = *(const float2*)&xr[2 * t];
  float s = v.x + v.y;
  #pragma unroll
  for (int m = 1; m < 64; m <<= 1) s += __shfl_xor(s, m);
  __shared__ float red1[4], red2[4];
  const int wv = t >> 6, lane = t & 63;
  if (lane == 0) red1[wv] = s;
  __syncthreads();
  const float mu = (red1[0] + red1[1] + red1[2] + red1[3]) * (1.0f / 512.0f);
  const float dx = v.x - mu, dy = v.y - mu;
  float q = dx * dx + dy * dy;
  #pragma unroll
  for (int m = 1; m < 64; m <<= 1) q += __shfl_xor(q, m);
  if (lane == 0) red2[wv] = q;
  __syncthreads();
  const float var = (red2[0] + red2[1] + red2[2] + red2[3]) * (1.0f / 512.0f);
  const float rs = rsqrtf(var + 1e-4f);
  float2 gg = *(const float2*)&gam[2 * t];
  float2 bb = *(const float2*)&be[2 * t];
  float2 o;
  o.x = gg.x * dx * rs + bb.x;
  o.y = gg.y * dy * rs + bb.y;
  *(float2*)&xr[2 * t] = o;
}

// ---------- ||k||^2 per (b,h,m) from split-bf16 K ----------
__global__ __launch_bounds__(256)
void knorm_bf(const ushort* __restrict__ kh, const ushort* __restrict__ kl,
              float* __restrict__ nb) {
  const int i = blockIdx.x * 256 + threadIdx.x;      // 32768
  const int b = i >> 13, h = (i >> 10) & 7, m = i & 1023;
  const ushort* ph = &kh[((size_t)(b * 1024 + m)) * 512 + h * 64];
  const ushort* pl = &kl[((size_t)(b * 1024 + m)) * 512 + h * 64];
  float s = 0.f;
  #pragma unroll
  for (int j = 0; j < 8; ++j) {
    uint4 uh = *(const uint4*)&ph[j << 3];
    uint4 ul = *(const uint4*)&pl[j << 3];
    uint hw[4] = {uh.x, uh.y, uh.z, uh.w};
    uint lw[4] = {ul.x, ul.y, ul.z, ul.w};
    #pragma unroll
    for (int e = 0; e < 4; ++e) {
      float a = bh2f((ushort)hw[e]) + bh2f((ushort)lw[e]);
      float c = bh2f((ushort)(hw[e] >> 16)) + bh2f((ushort)(lw[e] >> 16));
      s += a * a + c * c;
    }
  }
  nb[i] = s;
}

// ---------- MFMA attention: block = (128 q-rows, one (b,h)) ----------
// score = sqrt(max(na+nb-2qk,1e-7))*0.125; single-pass softmax (score<=~1,
// exp cannot overflow). QK^T and PV on MFMA; Q,K,V split-bf16; P single bf16.
// rs accumulates the SAME bf16-rounded p that feeds PV => O is an exact
// convex combination of the weights actually used (num/den consistent).
__global__ __launch_bounds__(256)
void attn_bf(const float* __restrict__ qbuf, const ushort* __restrict__ kh,
             const ushort* __restrict__ kl, const ushort* __restrict__ vth,
             const ushort* __restrict__ vtl, const float* __restrict__ nbuf,
             float* __restrict__ aout) {
  __shared__ ushort Kh[64][72], Kl[64][72], Vh[64][72], Vl[64][72];
  __shared__ ushort Ps[128][72];
  const int t = threadIdx.x, lane = t & 63, w = t >> 6;
  const int g = lane >> 4, cl = lane & 15;
  const int bh = blockIdx.y, b = bh >> 3, h = bh & 7;
  const int q0 = blockIdx.x << 7;     // block q base
  const int wq = q0 + (w << 5);       // wave q base (32 rows)

  // Q fragments (A-layout: row = lane&15, k = (lane>>4)*8 + j) + ||q||^2
  bh8 qh[2][2], ql[2][2];
  float naf[2];
  #pragma unroll
  for (int qs = 0; qs < 2; ++qs) {
    float nasum = 0.f;
    #pragma unroll
    for (int c = 0; c < 2; ++c) {
      const float* qp = &qbuf[((size_t)(b * 4096 + wq + (qs << 4) + cl)) * 512 +
                              h * 64 + (c << 5) + (g << 3)];
      float4 v0 = *(const float4*)qp;
      float4 v1 = *(const float4*)(qp + 4);
      float vv[8] = {v0.x, v0.y, v0.z, v0.w, v1.x, v1.y, v1.z, v1.w};
      bh8 hv, lv;
      #pragma unroll
      for (int j = 0; j < 8; ++j) {
        ushort hh, ll;
        split2(vv[j], hh, ll);
        hv[j] = (short)hh; lv[j] = (short)ll;
        nasum += vv[j] * vv[j];
      }
      qh[qs][c] = hv; ql[qs][c] = lv;
    }
    nasum += __shfl_xor(nasum, 16);
    nasum += __shfl_xor(nasum, 32);
    naf[qs] = nasum;                  // na for q-row = lane&15
  }
  float na_d[2][4];                   // remap to D-layout rows (g*4+r)
  #pragma unroll
  for (int qs = 0; qs < 2; ++qs)
    #pragma unroll
    for (int r = 0; r < 4; ++r)
      na_d[qs][r] = __shfl(naf[qs], (g << 2) + r);

  f32x4 oacc[2][4];
  #pragma unroll
  for (int i = 0; i < 2; ++i)
    #pragma unroll
    for (int j = 0; j < 4; ++j) oacc[i][j] = (f32x4)0.f;
  float rs[2][4] = {};

  for (int mt = 0; mt < 16; ++mt) {
    const int m0 = mt << 6;
    __syncthreads();                  // prior tile's K/V reads done
    {                                 // stage K,V (pure copy, pre-split bf16)
      int row = t >> 2, q16 = (t & 3) << 4;
      const ushort* kp = &kh[((size_t)(b * 1024 + m0 + row)) * 512 + h * 64 + q16];
      *(uint4*)&Kh[row][q16]     = *(const uint4*)kp;
      *(uint4*)&Kh[row][q16 + 8] = *(const uint4*)(kp + 8);
      const ushort* kq = &kl[((size_t)(b * 1024 + m0 + row)) * 512 + h * 64 + q16];
      *(uint4*)&Kl[row][q16]     = *(const uint4*)kq;
      *(uint4*)&Kl[row][q16 + 8] = *(const uint4*)(kq + 8);
      const ushort* vp = &vth[(((size_t)(b * 8 + h) << 6) + row) * 1024 + m0 + q16];
      *(uint4*)&Vh[row][q16]     = *(const uint4*)vp;
      *(uint4*)&Vh[row][q16 + 8] = *(const uint4*)(vp + 8);
      const ushort* vq = &vtl[(((size_t)(b * 8 + h) << 6) + row) * 1024 + m0 + q16];
      *(uint4*)&Vl[row][q16]     = *(const uint4*)vq;
      *(uint4*)&Vl[row][q16 + 8] = *(const uint4*)(vq + 8);
    }
    float nb[4];
    #pragma unroll
    for (int ms = 0; ms < 4; ++ms)
      nb[ms] = nbuf[(size_t)bh * 1024 + m0 + (ms << 4) + cl];
    __syncthreads();

    // S = Q K^T (split-3)
    f32x4 sa[2][4];
    #pragma unroll
    for (int i = 0; i < 2; ++i)
      #pragma unroll
      for (int j = 0; j < 4; ++j) sa[i][j] = (f32x4)0.f;
    #pragma unroll
    for (int c = 0; c < 2; ++c)
      #pragma unroll
      for (int ms = 0; ms < 4; ++ms) {
        bh8 kfh = *(const bh8*)&Kh[(ms << 4) + cl][(c << 5) + (g << 3)];
        bh8 kfl = *(const bh8*)&Kl[(ms << 4) + cl][(c << 5) + (g << 3)];
        #pragma unroll
        for (int qs = 0; qs < 2; ++qs) {
          sa[qs][ms] = MFMA16(qh[qs][c], kfh, sa[qs][ms]);
          sa[qs][ms] = MFMA16(qh[qs][c], kfl, sa[qs][ms]);
          sa[qs][ms] = MFMA16(ql[qs][c], kfh, sa[qs][ms]);
        }
      }

    // softmax transform; write P (bf16) to wave-private Ps rows
    #pragma unroll
    for (int qs = 0; qs < 2; ++qs)
      #pragma unroll
      for (int ms = 0; ms < 4; ++ms)
        #pragma unroll
        for (int r = 0; r < 4; ++r) {
          float d2 = na_d[qs][r] + nb[ms] - 2.0f * sa[qs][ms][r];
          float p = __expf(sqrtf(fmaxf(d2, 1e-7f)) * 0.125f);
          ushort pb = f2bh(p);
          rs[qs][r] += bh2f(pb);      // accumulate the value PV will use
          Ps[(w << 5) + (qs << 4) + (g << 2) + r][(ms << 4) + cl] = pb;
        }

    // O += P V  (Ps rows wave-private -> no barrier; V stable since stage)
    #pragma unroll
    for (int c = 0; c < 2; ++c) {
      bh8 pf0 = *(const bh8*)&Ps[(w << 5) + cl][(c << 5) + (g << 3)];
      bh8 pf1 = *(const bh8*)&Ps[(w << 5) + 16 + cl][(c << 5) + (g << 3)];
      #pragma unroll
      for (int ds = 0; ds < 4; ++ds) {
        bh8 vfh = *(const bh8*)&Vh[(ds << 4) + cl][(c << 5) + (g << 3)];
        bh8 vfl = *(const bh8*)&Vl[(ds << 4) + cl][(c << 5) + (g << 3)];
        oacc[0][ds] = MFMA16(pf0, vfh, oacc[0][ds]);
        oacc[0][ds] = MFMA16(pf0, vfl, oacc[0][ds]);
        oacc[1][ds] = MFMA16(pf1, vfh, oacc[1][ds]);
        oacc[1][ds] = MFMA16(pf1, vfl, oacc[1][ds]);
      }
    }
  }

  // row sums -> normalize -> store
  #pragma unroll
  for (int qs = 0; qs < 2; ++qs)
    #pragma unroll
    for (int r = 0; r < 4; ++r) {
      float v = rs[qs][r];
      v += __shfl_xor(v, 1); v += __shfl_xor(v, 2);
      v += __shfl_xor(v, 4); v += __shfl_xor(v, 8);
      rs[qs][r] = 1.0f / v;
    }
  #pragma unroll
  for (int qs = 0; qs < 2; ++qs)
    #pragma unroll
    for (int ds = 0; ds < 4; ++ds)
      #pragma unroll
      for (int r = 0; r < 4; ++r)
        aout[((size_t)(b * 4096 + wq + (qs << 4) + (g << 2) + r)) * 512 +
             h * 64 + (ds << 4) + cl] = oacc[qs][ds][r] * rs[qs][r];
}

extern "C" void kernel_launch(void* const* d_in, const int* in_sizes, int n_in,
                              void* d_out, int out_size, void* d_ws, size_t ws_size,
                              hipStream_t stream) {
  const float* x     = (const float*)d_in[0];
  const float* Wq    = (const float*)d_in[1];
  const float* Wkv   = (const float*)d_in[2];
  const float* convw = (const float*)d_in[3];
  const float* gamma = (const float*)d_in[4];
  const float* beta  = (const float*)d_in[5];
  const float* Wproj = (const float*)d_in[6];
  float* out = (float*)d_out;
  float* ws  = (float*)d_ws;

  // ws layout (float offsets), total 12,615,680 floats = 48.13 MiB —
  // identical footprint to the PROVEN round-3 run (do not grow: ws overflow
  // faults the GPU and kills the container).
  // region1 (16.1 MiB): split-bf16 K / V^T + nbuf. Dead after kernel 6;
  //   Wproj^T is prepped into its head AFTER attention (kernel 6.5).
  ushort* khbuf = (ushort*)(ws + 0);             // [4][1024][512] u16
  ushort* klbuf = (ushort*)(ws + 1048576);
  ushort* vthb  = (ushort*)(ws + 2097152);       // [4][8][64][1024] u16
  ushort* vtlb  = (ushort*)(ws + 3145728);
  float*  nbuf  = ws + 4194304;                  // [4][8][1024]
  ushort* wpTh  = (ushort*)(ws + 0);             // Wproj^T hi [512][512]
  ushort* wpTl  = (ushort*)(ws + 131072);        //   (written after attn)
  // region3 (32 MiB): xln + transient weight copies, later fully overwritten
  // by aout (conv/q/kv weights dead before attention writes aout).
  float*  r3    = ws + 4227072;
  float*  xln   = r3;                            // [4][1024][512]
  ushort* cwTh  = (ushort*)(r3 + 2097152);       // convW^T hi [512][2048]
  ushort* cwTl  = (ushort*)(r3 + 2621440);
  ushort* wqTh  = (ushort*)(r3 + 3145728);       // Wq^T hi [512][512]
  ushort* wqTl  = (ushort*)(r3 + 3276800);
  ushort* wkvTh = (ushort*)(r3 + 3407872);       // Wkv^T hi [1024][512]
  ushort* wkvTl = (ushort*)(r3 + 3670016);
  float*  aout  = r3;                            // [4][4096][512] (attn output)
  float*  qbuf  = out;   // q lives in d_out; dead before final GEMM overwrites

  // 0. weight transpose+split (Wproj deferred until after attention)
  prep_wT<<<dim3(256),  256, 0, stream>>>(Wq,    wqTh,  wqTl,  512,  512);
  prep_wT<<<dim3(512),  256, 0, stream>>>(Wkv,   wkvTh, wkvTl, 512,  1024);
  prep_wT<<<dim3(1024), 256, 0, stream>>>(convw, cwTh,  cwTl,  2048, 512);
  // 1. q projection -> d_out
  gemm_bf3<0><<<dim3(4, 128), 256, 0, stream>>>(x, wqTh, wqTl, qbuf,
      16384, 512, 512, nullptr, nullptr, nullptr, nullptr);
  // 2. SR conv -> xln
  conv_bf3<<<dim3(4, 32), 256, 0, stream>>>(x, cwTh, cwTl, xln);
  // 3. LayerNorm in place
  ln_rows<<<dim3(4096), 256, 0, stream>>>(xln, gamma, beta);
  // 4. kv projection -> split K + transposed split V
  gemm_bf3<1><<<dim3(8, 32), 256, 0, stream>>>(xln, wkvTh, wkvTl, nullptr,
      4096, 1024, 512, khbuf, klbuf, vthb, vtlb);
  // 5. ||k||^2
  knorm_bf<<<dim3(128), 256, 0, stream>>>(khbuf, klbuf, nbuf);
  // 6. attention -> aout
  attn_bf<<<dim3(32, 32), 256, 0, stream>>>(qbuf, khbuf, klbuf, vthb, vtlb,
                                            nbuf, aout);
  // 6.5 Wproj transpose+split into region1 head (K/V dead now)
  prep_wT<<<dim3(256),  256, 0, stream>>>(Wproj, wpTh,  wpTl,  512,  512);
  // 7. output projection -> d_out
  gemm_bf3<0><<<dim3(4, 128), 256, 0, stream>>>(aout, wpTh, wpTl, out,
      16384, 512, 512, nullptr, nullptr, nullptr, nullptr);
}